// Round 11
// baseline (23009.500 us; speedup 1.0000x reference)
//
#include <hip/hip_runtime.h>

// ---------------------------------------------------------------------------
// TextClassification: embedding -> LSTM(2048 steps) -> linear head
// V=50257 D=256 H=256 O=10 L=2048 N=64
//
// 2 chunks of 1024 steps (gates chunk = 134 MB of the 256 MiB ws):
//   Phase A: fp16 MFMA GEMM gates[m][p] = emb[x[m]].Wx[p] + (bx+bh)[p]
//   Phase B: CHAIN PAIRING - 32 blocks, 2 chains each (weights are shared
//     across the batch: every weight fetched is used twice -> 2x arithmetic
//     intensity, dual independent dot chains hide memory latency).
//     512 threads, thread=(j,kh). Per kh-half kc tiers (16 kc each):
//       rel 0-3  : resident in VGPRs (16 half8 = 64 regs)
//       rel 4-7  : 128 KB LDS cache
//       rel 8-15 : streamed from L2, 2-slot ring, S/L/S/R interleave ->
//                  slot reuse distance 4 groups (~350 cyc >= L2 latency;
//                  round-10 bug was 2-group spacing -> stalls)
//     Combine tail parallel: kh0 finishes chain A, kh1 finishes chain B.
//     Barriers: raw s_barrier + lgkmcnt(0), no memory clobber (keeps
//     stream/gate loads in flight across barriers).
//   Phase C: folded into last chunk tail (both chains).
// ---------------------------------------------------------------------------

using half_t  = _Float16;
using half2_t = __attribute__((ext_vector_type(2))) _Float16;
using half8_t = __attribute__((ext_vector_type(8))) _Float16;
using f32x4   = __attribute__((ext_vector_type(4))) float;

#define L_SEQ   2048
#define CHUNK_L 1024
#define NB      64
#define DIM     256
#define P4      1024                 // 4 gates * H
#define CM      (CHUNK_L * NB)       // 65536 rows per chunk

// workspace layout (bytes)
#define OFF_GATES 0ull
#define SZ_GATES  ((unsigned long long)CM * P4 * 2)        // 134217728
#define OFF_EMBH  (OFF_GATES + SZ_GATES)
#define SZ_EMBH   (50257ull * 256 * 2)                     // 25731584
#define OFF_WX    (OFF_EMBH + SZ_EMBH)
#define SZ_WX     (1024ull * 256 * 2)
#define OFF_WH    (OFF_WX + SZ_WX)
#define SZ_WH     (1024ull * 256 * 2)
#define OFF_B4    (OFF_WH + SZ_WH)
#define SZ_B4     (1024ull * 4)
#define OFF_ST    (OFF_B4 + SZ_B4)
#define SZ_ST     (2ull * NB * DIM * 4)                    // h,c f32 state
#define WS_NEED   (OFF_ST + SZ_ST)                         // ~161.1 MB

// ---------------- helpers ----------------
__device__ __forceinline__ float sigm(float x) {
  x = fminf(fmaxf(x, -30.f), 30.f);
  return 1.f / (1.f + __expf(-x));
}
__device__ __forceinline__ float tanh_(float x) {
  x = fminf(fmaxf(x, -15.f), 15.f);
  float t = __expf(2.f * x);
  return (t - 1.f) / (t + 1.f);
}
__device__ __forceinline__ float dot8(half8_t w, half8_t h, float acc) {
  acc = __builtin_amdgcn_fdot2((half2_t)__builtin_shufflevector(w, w, 0, 1),
                               (half2_t)__builtin_shufflevector(h, h, 0, 1), acc, false);
  acc = __builtin_amdgcn_fdot2((half2_t)__builtin_shufflevector(w, w, 2, 3),
                               (half2_t)__builtin_shufflevector(h, h, 2, 3), acc, false);
  acc = __builtin_amdgcn_fdot2((half2_t)__builtin_shufflevector(w, w, 4, 5),
                               (half2_t)__builtin_shufflevector(h, h, 4, 5), acc, false);
  acc = __builtin_amdgcn_fdot2((half2_t)__builtin_shufflevector(w, w, 6, 7),
                               (half2_t)__builtin_shufflevector(h, h, 6, 7), acc, false);
  return acc;
}

// LDS-only barrier, NO memory clobber -> vmcnt untouched
#define SBAR() do {                                   \
    __builtin_amdgcn_sched_barrier(0);                \
    asm volatile("s_waitcnt lgkmcnt(0)" ::);          \
    __builtin_amdgcn_s_barrier();                     \
    __builtin_amdgcn_sched_barrier(0);                \
  } while (0)

// ---------------- kernels ----------------
__global__ void ws_too_small_kernel(float* out, float sz) {
  if (threadIdx.x == 0 && blockIdx.x == 0) out[0] = sz;
}

__global__ void cvt_emb_kernel(const float* __restrict__ src, half_t* __restrict__ dst,
                               int total8) {
  int i = blockIdx.x * blockDim.x + threadIdx.x;
  if (i >= total8) return;
  const float4* s = (const float4*)src + (size_t)i * 2;
  float4 a = s[0], b = s[1];
  half8_t o;
  o[0] = (half_t)a.x; o[1] = (half_t)a.y; o[2] = (half_t)a.z; o[3] = (half_t)a.w;
  o[4] = (half_t)b.x; o[5] = (half_t)b.y; o[6] = (half_t)b.z; o[7] = (half_t)b.w;
  *((half8_t*)dst + i) = o;
}

// Wx4h[p][k] row-major fp16; Wh4c[(k>>3)][p][k&7]; b4 = bx + bh
__global__ void pack_w_kernel(const float* __restrict__ Wii, const float* __restrict__ Whi,
                              const float* __restrict__ Wif, const float* __restrict__ Whf,
                              const float* __restrict__ Wig, const float* __restrict__ Whg,
                              const float* __restrict__ Wio, const float* __restrict__ Who,
                              const float* __restrict__ bii, const float* __restrict__ bhi,
                              const float* __restrict__ bif, const float* __restrict__ bhf,
                              const float* __restrict__ big_, const float* __restrict__ bhg,
                              const float* __restrict__ bio, const float* __restrict__ bho,
                              half_t* __restrict__ Wx4h, half_t* __restrict__ Wh4c,
                              float* __restrict__ b4) {
  int p = blockIdx.x;   // 0..1023
  int k = threadIdx.x;  // 0..255
  int g = p >> 8, h = p & 255;
  const float* Wx = g == 0 ? Wii : g == 1 ? Wif : g == 2 ? Wig : Wio;
  const float* Wh = g == 0 ? Whi : g == 1 ? Whf : g == 2 ? Whg : Who;
  Wx4h[(size_t)p * DIM + k] = (half_t)Wx[h * DIM + k];
  Wh4c[((size_t)(k >> 3) * P4 + p) * 8 + (k & 7)] = (half_t)Wh[h * DIM + k];
  if (k == 0) {
    const float* bx = g == 0 ? bii : g == 1 ? bif : g == 2 ? big_ : bio;
    const float* bh = g == 0 ? bhi : g == 1 ? bhf : g == 2 ? bhg : bho;
    b4[p] = bx[h] + bh[h];
  }
}

// Phase A GEMM (unchanged; 128x128 tile, mfma_f32_16x16x32_f16)
#define BK   32
#define LSTR 40
__global__ __launch_bounds__(256) void gemm_gates_kernel(
    const half_t* __restrict__ embh, const int* __restrict__ xc,
    const half_t* __restrict__ Wx4h, const float* __restrict__ b4,
    half_t* __restrict__ gates) {
  __shared__ __align__(16) half_t As[128 * LSTR];
  __shared__ __align__(16) half_t Ws[128 * LSTR];
  const int tid  = threadIdx.x;
  const int lane = tid & 63;
  const int wave = tid >> 6;
  const int wm = wave >> 1, wn = wave & 1;
  const int M0 = blockIdx.x * 128;
  const int P0 = blockIdx.y * 128;
  const int r0 = tid >> 2, s0 = tid & 3;

  const size_t arow0 = (size_t)xc[M0 + r0] * DIM;
  const size_t arow1 = (size_t)xc[M0 + 64 + r0] * DIM;
  const size_t wrow0 = (size_t)(P0 + r0) * DIM;
  const size_t wrow1 = (size_t)(P0 + 64 + r0) * DIM;

  f32x4 acc[4][4] = {};
  const int fr = lane & 15;
  const int kq = lane >> 4;

  for (int kt = 0; kt < 8; ++kt) {
    const int k0 = kt * BK;
    half8_t a0 = *(const half8_t*)(embh + arow0 + k0 + s0 * 8);
    half8_t a1 = *(const half8_t*)(embh + arow1 + k0 + s0 * 8);
    half8_t w0 = *(const half8_t*)(Wx4h + wrow0 + k0 + s0 * 8);
    half8_t w1 = *(const half8_t*)(Wx4h + wrow1 + k0 + s0 * 8);
    __syncthreads();
    *(half8_t*)(As + r0 * LSTR + s0 * 8)        = a0;
    *(half8_t*)(As + (r0 + 64) * LSTR + s0 * 8) = a1;
    *(half8_t*)(Ws + r0 * LSTR + s0 * 8)        = w0;
    *(half8_t*)(Ws + (r0 + 64) * LSTR + s0 * 8) = w1;
    __syncthreads();
    half8_t af[4], bf[4];
#pragma unroll
    for (int mi = 0; mi < 4; ++mi)
      af[mi] = *(const half8_t*)(As + (wm * 64 + mi * 16 + fr) * LSTR + kq * 8);
#pragma unroll
    for (int ni = 0; ni < 4; ++ni)
      bf[ni] = *(const half8_t*)(Ws + (wn * 64 + ni * 16 + fr) * LSTR + kq * 8);
#pragma unroll
    for (int mi = 0; mi < 4; ++mi)
#pragma unroll
      for (int ni = 0; ni < 4; ++ni)
        acc[mi][ni] = __builtin_amdgcn_mfma_f32_16x16x32_f16(af[mi], bf[ni], acc[mi][ni], 0, 0, 0);
  }
  const int rbase = (lane >> 4) * 4;
#pragma unroll
  for (int ni = 0; ni < 4; ++ni) {
    const int p = P0 + wn * 64 + ni * 16 + fr;
    const float bias = b4[p];
#pragma unroll
    for (int mi = 0; mi < 4; ++mi) {
      const int m = M0 + wm * 64 + mi * 16 + rbase;
#pragma unroll
      for (int r = 0; r < 4; ++r)
        gates[(size_t)(m + r) * P4 + p] = (half_t)(acc[mi][ni][r] + bias);
    }
  }
}

// ---- resident tier (rel 0..3): 16 half8 = 64 VGPRs ----
#define DECLR(r) half8_t R##r##_0, R##r##_1, R##r##_2, R##r##_3;
#define LOADR(r)                                   \
  R##r##_0 = W8[(kcb + (r)) * P4 + p0];            \
  R##r##_1 = W8[(kcb + (r)) * P4 + p1];            \
  R##r##_2 = W8[(kcb + (r)) * P4 + p2];            \
  R##r##_3 = W8[(kcb + (r)) * P4 + p3];
#define PINR(r)                                                             \
  asm volatile("" : "+v"(R##r##_0), "+v"(R##r##_1), "+v"(R##r##_2),         \
                    "+v"(R##r##_3));
#define RGRP(r) { const half8_t hA = hpA[r], hB = hpB[r];                   \
  aA0 = dot8(R##r##_0, hA, aA0); aB0 = dot8(R##r##_0, hB, aB0);             \
  aA1 = dot8(R##r##_1, hA, aA1); aB1 = dot8(R##r##_1, hB, aB1);             \
  aA2 = dot8(R##r##_2, hA, aA2); aB2 = dot8(R##r##_2, hB, aB2);             \
  aA3 = dot8(R##r##_3, hA, aA3); aB3 = dot8(R##r##_3, hB, aB3); }

// ---- LDS tier (rel 4..7): slot = kh*4 + (r-4) ----
#define LGRP(r) { const half8_t hA = hpA[r], hB = hpB[r];                   \
  const int sl = (kh << 2) + (r) - 4;                                       \
  const half8_t w0 = *(const half8_t*)wlds[sl][p0];                         \
  const half8_t w1 = *(const half8_t*)wlds[sl][p1];                         \
  const half8_t w2 = *(const half8_t*)wlds[sl][p2];                         \
  const half8_t w3 = *(const half8_t*)wlds[sl][p3];                         \
  aA0 = dot8(w0, hA, aA0); aB0 = dot8(w0, hB, aB0);                         \
  aA1 = dot8(w1, hA, aA1); aB1 = dot8(w1, hB, aB1);                         \
  aA2 = dot8(w2, hA, aA2); aB2 = dot8(w2, hB, aB2);                         \
  aA3 = dot8(w3, hA, aA3); aB3 = dot8(w3, hB, aB3); }

// ---- stream tier (rel 8..15): consume slot, reissue for rel rn ----
#define SGRP(r, s0_, s1_, s2_, s3_, rn) { const half8_t hA = hpA[r], hB = hpB[r]; \
  aA0 = dot8(s0_, hA, aA0); aB0 = dot8(s0_, hB, aB0); s0_ = W8[(kcb + (rn)) * P4 + p0]; \
  aA1 = dot8(s1_, hA, aA1); aB1 = dot8(s1_, hB, aB1); s1_ = W8[(kcb + (rn)) * P4 + p1]; \
  aA2 = dot8(s2_, hA, aA2); aB2 = dot8(s2_, hB, aB2); s2_ = W8[(kcb + (rn)) * P4 + p2]; \
  aA3 = dot8(s3_, hA, aA3); aB3 = dot8(s3_, hB, aB3); s3_ = W8[(kcb + (rn)) * P4 + p3]; }

// Phase B: 32 blocks, chains nA=2b / nB=2b+1. 512 threads, thread=(j,kh).
__global__ __launch_bounds__(512)
void lstm2_kernel(const half_t* __restrict__ gates, const half_t* __restrict__ Wh4c,
                  const float* __restrict__ Wout, const float* __restrict__ bout,
                  float* __restrict__ out, float* __restrict__ state,
                  int first, int last) {
  const int b   = blockIdx.x;
  const int nA  = 2 * b, nB = 2 * b + 1;
  const int tid = threadIdx.x;
  const int j   = tid & 255;
  const int kh  = tid >> 8;
  const int ns  = kh == 0 ? nA : nB;   // chain this thread finishes
  __shared__ __align__(16) half_t wlds[8][P4][8];    // 128 KB: abs kc {4-7,20-23}
  __shared__ __align__(16) half_t hbufA[2][DIM];     // 1 KB
  __shared__ __align__(16) half_t hbufB[2][DIM];     // 1 KB
  __shared__ __align__(16) float  pexA[DIM][4];      // 4 KB (kh1's A-partials)
  __shared__ __align__(16) float  pexB[DIM][4];      // 4 KB (kh0's B-partials)

  const half8_t* W8 = (const half8_t*)Wh4c;
  // LDS weight cache fill: slot s -> abs kc = (s>>2)*16 + 4 + (s&3)
  for (int i = tid; i < 8192; i += 512) {
    const int s = i >> 10, pp = i & 1023;
    const int kc = ((s >> 2) << 4) + 4 + (s & 3);
    *(half8_t*)wlds[s][pp] = W8[kc * P4 + pp];
  }
  const int kcb = kh << 4;
  const int p0 = j, p1 = 256 + j, p2 = 512 + j, p3 = 768 + j;

  DECLR(0) DECLR(1) DECLR(2) DECLR(3)
  LOADR(0) LOADR(1) LOADR(2) LOADR(3)
  PINR(0) PINR(1) PINR(2) PINR(3)
  // ring prime: slot A <- rel 8, slot B <- rel 9
  half8_t SA0 = W8[(kcb + 8) * P4 + p0], SA1 = W8[(kcb + 8) * P4 + p1];
  half8_t SA2 = W8[(kcb + 8) * P4 + p2], SA3 = W8[(kcb + 8) * P4 + p3];
  half8_t TB0 = W8[(kcb + 9) * P4 + p0], TB1 = W8[(kcb + 9) * P4 + p1];
  half8_t TB2 = W8[(kcb + 9) * P4 + p2], TB3 = W8[(kcb + 9) * P4 + p3];

  // my chain's state + gates (kh0 -> A, kh1 -> B)
  float cc = 0.f, hkeep = 0.f;
  {
    float h0 = 0.f;
    if (!first) { h0 = state[ns * DIM + j]; cc = state[NB * DIM + ns * DIM + j]; }
    half_t* hw0 = kh == 0 ? &hbufA[0][j] : &hbufB[0][j];
    *hw0 = (half_t)h0;
    hkeep = h0;
  }
  const half_t* gbase = gates + (size_t)ns * P4;
  float g0f = (float)gbase[p0], g1f = (float)gbase[p1];
  float g2f = (float)gbase[p2], g3f = (float)gbase[p3];
  __syncthreads();

  int par = 0;
#pragma unroll 1
  for (int l = 0; l < CHUNK_L; ++l) {
    float aA0 = 0.f, aA1 = 0.f, aA2 = 0.f, aA3 = 0.f;
    float aB0 = 0.f, aB1 = 0.f, aB2 = 0.f, aB3 = 0.f;
    // issue next-period gate loads early (in flight across the period)
    const half_t* gp2 = gbase + (size_t)(l + 1) * (NB * P4);  // last read: embh, ok
    half_t ng0 = gp2[p0], ng1 = gp2[p1], ng2 = gp2[p2], ng3 = gp2[p3];
    const half8_t* hpA = (const half8_t*)hbufA[par] + kcb;
    const half8_t* hpB = (const half8_t*)hbufB[par] + kcb;
    // 16 groups: stream interleaved with LDS then resident; ring slots
    // alternate -> reuse distance 4 groups (~350 cyc)
    SGRP(8,  SA0, SA1, SA2, SA3, 10) LGRP(4)
    SGRP(9,  TB0, TB1, TB2, TB3, 11) LGRP(5)
    SGRP(10, SA0, SA1, SA2, SA3, 12) LGRP(6)
    SGRP(11, TB0, TB1, TB2, TB3, 13) LGRP(7)
    SGRP(12, SA0, SA1, SA2, SA3, 14) RGRP(0)
    SGRP(13, TB0, TB1, TB2, TB3, 15) RGRP(1)
    SGRP(14, SA0, SA1, SA2, SA3, 8)  RGRP(2)   // wrap: reload for next period
    SGRP(15, TB0, TB1, TB2, TB3, 9)  RGRP(3)
    // publish the OTHER chain's partials (kh0 computed B too, kh1 computed A)
    {
      float4 pv;
      if (kh == 0) { pv.x = aB0; pv.y = aB1; pv.z = aB2; pv.w = aB3;
                     *(float4*)pexB[j] = pv; }
      else         { pv.x = aA0; pv.y = aA1; pv.z = aA2; pv.w = aA3;
                     *(float4*)pexA[j] = pv; }
    }
    SBAR();                      // partials visible; stream stays in flight
    {
      const float o0 = kh == 0 ? aA0 : aB0;
      const float o1 = kh == 0 ? aA1 : aB1;
      const float o2 = kh == 0 ? aA2 : aB2;
      const float o3 = kh == 0 ? aA3 : aB3;
      const float* pex = kh == 0 ? pexA[j] : pexB[j];
      float4 pv = *(const float4*)pex;
      const float ai  = o0 + pv.x + g0f;
      const float af_ = o1 + pv.y + g1f;
      const float ag  = o2 + pv.z + g2f;
      const float ao  = o3 + pv.w + g3f;
      cc = sigm(af_) * cc + sigm(ai) * tanh_(ag);
      const float h = sigm(ao) * tanh_(cc);
      half_t* hw = kh == 0 ? &hbufA[par ^ 1][j] : &hbufB[par ^ 1][j];
      *hw = (half_t)h;
      hkeep = h;
      g0f = (float)ng0; g1f = (float)ng1; g2f = (float)ng2; g3f = (float)ng3;
    }
    SBAR();                      // h published
    par ^= 1;
  }
  __syncthreads();
  if (!last) {
    state[ns * DIM + j] = hkeep;
    state[NB * DIM + ns * DIM + j] = cc;
  }
  if (last && j < 10) {
    const half_t* hb = kh == 0 ? hbufA[0] : hbufB[0];
    float s = bout[j];
    const float* wrow = Wout + j * DIM;
#pragma unroll 4
    for (int k = 0; k < DIM; ++k) s += (float)hb[k] * wrow[k];
    out[ns * 10 + j] = s;
  }
}

// ---------------- launch ----------------
extern "C" void kernel_launch(void* const* d_in, const int* in_sizes, int n_in,
                              void* d_out, int out_size, void* d_ws, size_t ws_size,
                              hipStream_t stream) {
  const int*   x    = (const int*)d_in[0];
  const float* emb  = (const float*)d_in[1];
  const float* Wii  = (const float*)d_in[2];  const float* bii = (const float*)d_in[3];
  const float* Whi  = (const float*)d_in[4];  const float* bhi = (const float*)d_in[5];
  const float* Wif  = (const float*)d_in[6];  const float* bif = (const float*)d_in[7];
  const float* Whf  = (const float*)d_in[8];  const float* bhf = (const float*)d_in[9];
  const float* Wig  = (const float*)d_in[10]; const float* big_ = (const float*)d_in[11];
  const float* Whg  = (const float*)d_in[12]; const float* bhg = (const float*)d_in[13];
  const float* Wio  = (const float*)d_in[14]; const float* bio = (const float*)d_in[15];
  const float* Who  = (const float*)d_in[16]; const float* bho = (const float*)d_in[17];
  const float* Wout = (const float*)d_in[18]; const float* bout = (const float*)d_in[19];
  float* out = (float*)d_out;

  if (ws_size < WS_NEED) {  // fail loudly but safely: absmax will show ws_size
    hipLaunchKernelGGL(ws_too_small_kernel, dim3(1), dim3(64), 0, stream, out, (float)ws_size);
    return;
  }
  char* ws = (char*)d_ws;
  half_t* gates = (half_t*)(ws + OFF_GATES);
  half_t* embh  = (half_t*)(ws + OFF_EMBH);
  half_t* Wx4h  = (half_t*)(ws + OFF_WX);
  half_t* Wh4c  = (half_t*)(ws + OFF_WH);
  float*  b4    = (float*)(ws + OFF_B4);
  float*  state = (float*)(ws + OFF_ST);

  const int total8 = 50257 * 32;  // V*D/8
  hipLaunchKernelGGL(cvt_emb_kernel, dim3((total8 + 255) / 256), dim3(256), 0, stream,
                     emb, embh, total8);
  hipLaunchKernelGGL(pack_w_kernel, dim3(1024), dim3(256), 0, stream,
                     Wii, Whi, Wif, Whf, Wig, Whg, Wio, Who,
                     bii, bhi, bif, bhf, big_, bhg, bio, bho,
                     Wx4h, Wh4c, b4);
  // chunk 0: steps [0, 1024)
  hipLaunchKernelGGL(gemm_gates_kernel, dim3(CM / 128, P4 / 128), dim3(256), 0, stream,
                     embh, x, Wx4h, b4, gates);
  hipLaunchKernelGGL(lstm2_kernel, dim3(NB / 2), dim3(512), 0, stream,
                     gates, Wh4c, Wout, bout, out, state, 1, 0);
  // chunk 1: steps [1024, 2048)
  hipLaunchKernelGGL(gemm_gates_kernel, dim3(CM / 128, P4 / 128), dim3(256), 0, stream,
                     embh, x + (size_t)CHUNK_L * NB, Wx4h, b4, gates);
  hipLaunchKernelGGL(lstm2_kernel, dim3(NB / 2), dim3(512), 0, stream,
                     gates, Wh4c, Wout, bout, out, state, 0, 1);
}